// Round 1
// baseline (984.368 us; speedup 1.0000x reference)
//
#include <hip/hip_runtime.h>
#include <math.h>

#define D    256
#define D2   512
#define HH   8192
#define NAG  64
#define NROWS 2048
#define KS   4

__device__ __forceinline__ float gelu_f(float x) {
    return 0.5f * x * (1.0f + erff(x * 0.70710678118654752440f));
}
__device__ __forceinline__ float sigmoid_f(float x) {
    return 1.0f / (1.0f + expf(-x));
}

// ---------------------------------------------------------------- K1: perception
// mod = sig*(1+0.1*(pers+0.3*chr)); LN(concat(mod,act)) @ W_perc + b -> GELU
__global__ __launch_bounds__(256) void k_perception(
    const float* __restrict__ sig, const float* __restrict__ act,
    const float* __restrict__ pers, const float* __restrict__ chr,
    const float* __restrict__ lng, const float* __restrict__ lnb,
    const float* __restrict__ Wp, const float* __restrict__ bp,
    float* __restrict__ perc)
{
    __shared__ __align__(16) float xb[8][D2];
    __shared__ float red[256];
    const int t = threadIdx.x;
    const int r0 = blockIdx.x * 8;

    for (int r = 0; r < 8; ++r) {
        const int row = r0 + r;
        const int n = row & (NAG - 1);
        const float p = pers[n * D + t] + 0.3f * chr[n * D + t];
        xb[r][t]     = sig[row * D + t] * (1.0f + 0.1f * p);
        xb[r][t + D] = act[row * D + t];
    }
    __syncthreads();

    for (int r = 0; r < 8; ++r) {
        float a = xb[r][t], b = xb[r][t + D];
        red[t] = a + b; __syncthreads();
        for (int s = 128; s > 0; s >>= 1) { if (t < s) red[t] += red[t + s]; __syncthreads(); }
        const float mu = red[0] * (1.0f / 512.0f);
        __syncthreads();
        a -= mu; b -= mu;
        red[t] = a * a + b * b; __syncthreads();
        for (int s = 128; s > 0; s >>= 1) { if (t < s) red[t] += red[t + s]; __syncthreads(); }
        const float rstd = rsqrtf(red[0] * (1.0f / 512.0f) + 1e-5f);
        __syncthreads();
        xb[r][t]     = a * rstd * lng[t]     + lnb[t];
        xb[r][t + D] = b * rstd * lng[t + D] + lnb[t + D];
    }
    __syncthreads();

    float acc[8];
    #pragma unroll
    for (int r = 0; r < 8; ++r) acc[r] = 0.0f;
    for (int k4 = 0; k4 < D2 / 4; ++k4) {
        const int k = 4 * k4;
        const float w0 = Wp[(k + 0) * D + t];
        const float w1 = Wp[(k + 1) * D + t];
        const float w2 = Wp[(k + 2) * D + t];
        const float w3 = Wp[(k + 3) * D + t];
        #pragma unroll
        for (int r = 0; r < 8; ++r) {
            const float4 x = *reinterpret_cast<const float4*>(&xb[r][k]);
            acc[r] += x.x * w0 + x.y * w1 + x.z * w2 + x.w * w3;
        }
    }
    const float bb = bp[t];
    for (int r = 0; r < 8; ++r)
        perc[(r0 + r) * D + t] = gelu_f(acc[r] + bb);
}

// ---------------------------------------------------------------- K2: hdc_query GEMM fused with
// sim = sum((ep+cr)*key*q) and hdcdot = sum(q*W_mem[D:]) — q never materialized.
__global__ __launch_bounds__(256) void k_hdc_query(
    const float* __restrict__ perc, const float* __restrict__ Wh,
    const float* __restrict__ bh, const float* __restrict__ ep,
    const float* __restrict__ cr, const float* __restrict__ key,
    const float* __restrict__ Wm,
    float* __restrict__ sim_part, float* __restrict__ dot_part)
{
    __shared__ __align__(16) float xs[16][D];
    __shared__ float rb[16][256];
    const int t = threadIdx.x;
    const int r0 = blockIdx.y * 16;
    const int hbase = blockIdx.x * 512;

    for (int i = t; i < 16 * D; i += 256)
        xs[i >> 8][i & 255] = perc[(r0 + (i >> 8)) * D + (i & 255)];
    __syncthreads();

    const int h0 = hbase + t, h1 = hbase + 256 + t;
    float a0[16], a1[16];
    #pragma unroll
    for (int r = 0; r < 16; ++r) { a0[r] = 0.0f; a1[r] = 0.0f; }

    for (int k4 = 0; k4 < D / 4; ++k4) {
        const int k = 4 * k4;
        const float w00 = Wh[(k + 0) * HH + h0], w01 = Wh[(k + 1) * HH + h0],
                    w02 = Wh[(k + 2) * HH + h0], w03 = Wh[(k + 3) * HH + h0];
        const float w10 = Wh[(k + 0) * HH + h1], w11 = Wh[(k + 1) * HH + h1],
                    w12 = Wh[(k + 2) * HH + h1], w13 = Wh[(k + 3) * HH + h1];
        #pragma unroll
        for (int r = 0; r < 16; ++r) {
            const float4 x = *reinterpret_cast<const float4*>(&xs[r][k]);
            a0[r] += x.x * w00 + x.y * w01 + x.z * w02 + x.w * w03;
            a1[r] += x.x * w10 + x.y * w11 + x.z * w12 + x.w * w13;
        }
    }

    const float b0 = bh[h0], b1 = bh[h1];
    const float wm0 = Wm[D + h0], wm1 = Wm[D + h1];
    #pragma unroll
    for (int r = 0; r < 16; ++r) { a0[r] = tanhf(a0[r] + b0); a1[r] = tanhf(a1[r] + b1); }

    for (int r = 0; r < 16; ++r) {
        const int row = r0 + r, n = row & (NAG - 1);
        const float e0 = ep[row * HH + h0] + cr[row * HH + h0];
        const float e1 = ep[row * HH + h1] + cr[row * HH + h1];
        rb[r][t] = e0 * key[n * HH + h0] * a0[r] + e1 * key[n * HH + h1] * a1[r];
    }
    __syncthreads();
    for (int s = 128; s > 0; s >>= 1) {
        if (t < s) {
            #pragma unroll
            for (int r = 0; r < 16; ++r) rb[r][t] += rb[r][t + s];
        }
        __syncthreads();
    }
    if (t < 16) sim_part[blockIdx.x * NROWS + r0 + t] = rb[t][0];
    __syncthreads();

    for (int r = 0; r < 16; ++r) rb[r][t] = a0[r] * wm0 + a1[r] * wm1;
    __syncthreads();
    for (int s = 128; s > 0; s >>= 1) {
        if (t < s) {
            #pragma unroll
            for (int r = 0; r < 16; ++r) rb[r][t] += rb[r][t + s];
        }
        __syncthreads();
    }
    if (t < 16) dot_part[blockIdx.x * NROWS + r0 + t] = rb[t][0];
}

// ---------------------------------------------------------------- K3: recall GEMM (K=8192), K-split x4
__global__ __launch_bounds__(128) void k_recall(
    const float* __restrict__ ep, const float* __restrict__ cr,
    const float* __restrict__ Wf, float* __restrict__ rpart)
{
    __shared__ __align__(16) float xs[16][128];
    const int t = threadIdx.x;
    const int r0 = blockIdx.y * 16;
    const int kb0 = blockIdx.x * (HH / KS);

    float a0[16], a1[16];
    #pragma unroll
    for (int r = 0; r < 16; ++r) { a0[r] = 0.0f; a1[r] = 0.0f; }

    for (int ch = 0; ch < (HH / KS) / 128; ++ch) {
        const int kb = kb0 + ch * 128;
        __syncthreads();
        for (int i = t; i < 16 * 128; i += 128) {
            const int r = i >> 7, kk = i & 127;
            const int idx = (r0 + r) * HH + kb + kk;
            xs[r][kk] = ep[idx] + cr[idx];
        }
        __syncthreads();
        for (int k4 = 0; k4 < 32; ++k4) {
            const int k = kb + 4 * k4;
            const float w00 = Wf[(k + 0) * D + t],       w01 = Wf[(k + 1) * D + t],
                        w02 = Wf[(k + 2) * D + t],       w03 = Wf[(k + 3) * D + t];
            const float w10 = Wf[(k + 0) * D + t + 128], w11 = Wf[(k + 1) * D + t + 128],
                        w12 = Wf[(k + 2) * D + t + 128], w13 = Wf[(k + 3) * D + t + 128];
            #pragma unroll
            for (int r = 0; r < 16; ++r) {
                const float4 x = *reinterpret_cast<const float4*>(&xs[r][4 * k4]);
                a0[r] += x.x * w00 + x.y * w01 + x.z * w02 + x.w * w03;
                a1[r] += x.x * w10 + x.y * w11 + x.z * w12 + x.w * w13;
            }
        }
    }
    for (int r = 0; r < 16; ++r) {
        rpart[(blockIdx.x * NROWS + r0 + r) * D + t]       = a0[r];
        rpart[(blockIdx.x * NROWS + r0 + r) * D + t + 128] = a1[r];
    }
}

// ---------------------------------------------------------------- K4: decision / gate / LN / actions / mem_gate
__global__ __launch_bounds__(256) void k_decision(
    const float* __restrict__ perc, const float* __restrict__ rpart,
    const float* __restrict__ bfrom, const float* __restrict__ sim_part,
    const float* __restrict__ lng, const float* __restrict__ lnb,
    const float* __restrict__ Wd1, const float* __restrict__ bd1,
    const float* __restrict__ Wd2, const float* __restrict__ bd2,
    const float* __restrict__ pers, const float* __restrict__ prev,
    const float* __restrict__ Wg, const float* __restrict__ bg,
    const float* __restrict__ lnog, const float* __restrict__ lnob,
    const float* __restrict__ Wa, const float* __restrict__ ba,
    const float* __restrict__ Wm, const float* __restrict__ bm,
    const float* __restrict__ dot_part,
    float* __restrict__ out_act, float* __restrict__ out_st, float* __restrict__ out_mg)
{
    __shared__ __align__(16) float xb[8][D2];
    __shared__ __align__(16) float hb[8][D];
    __shared__ __align__(16) float db[8][D];
    __shared__ __align__(16) float nsb[8][D];
    __shared__ float red[256];
    const int t = threadIdx.x;
    const int r0 = blockIdx.x * 8;

    // 1. dec_in = concat(perception, recall)
    for (int r = 0; r < 8; ++r) {
        const int row = r0 + r;
        float sraw = 0.0f;
        for (int i = 0; i < 16; ++i) sraw += sim_part[i * NROWS + row];
        const float strength = sigmoid_f(sraw * (1.0f / (float)HH));
        float racc = 0.0f;
        for (int ksp = 0; ksp < KS; ++ksp) racc += rpart[(ksp * NROWS + row) * D + t];
        xb[r][t]     = perc[row * D + t];
        xb[r][t + D] = (racc + bfrom[t]) * strength;
    }
    __syncthreads();

    // 2. LN over 512
    for (int r = 0; r < 8; ++r) {
        float a = xb[r][t], b = xb[r][t + D];
        red[t] = a + b; __syncthreads();
        for (int s = 128; s > 0; s >>= 1) { if (t < s) red[t] += red[t + s]; __syncthreads(); }
        const float mu = red[0] * (1.0f / 512.0f);
        __syncthreads();
        a -= mu; b -= mu;
        red[t] = a * a + b * b; __syncthreads();
        for (int s = 128; s > 0; s >>= 1) { if (t < s) red[t] += red[t + s]; __syncthreads(); }
        const float rstd = rsqrtf(red[0] * (1.0f / 512.0f) + 1e-5f);
        __syncthreads();
        xb[r][t]     = a * rstd * lng[t]     + lnb[t];
        xb[r][t + D] = b * rstd * lng[t + D] + lnb[t + D];
    }
    __syncthreads();

    float acc[8];

    // 3. GEMM1 (K=512) + GELU -> hb
    #pragma unroll
    for (int r = 0; r < 8; ++r) acc[r] = 0.0f;
    for (int k4 = 0; k4 < D2 / 4; ++k4) {
        const int k = 4 * k4;
        const float w0 = Wd1[(k + 0) * D + t], w1 = Wd1[(k + 1) * D + t];
        const float w2 = Wd1[(k + 2) * D + t], w3 = Wd1[(k + 3) * D + t];
        #pragma unroll
        for (int r = 0; r < 8; ++r) {
            const float4 x = *reinterpret_cast<const float4*>(&xb[r][k]);
            acc[r] += x.x * w0 + x.y * w1 + x.z * w2 + x.w * w3;
        }
    }
    for (int r = 0; r < 8; ++r) hb[r][t] = gelu_f(acc[r] + bd1[t]);
    __syncthreads();

    // 4. GEMM2 (K=256) -> decision; refill xb = concat(prev, decision)
    #pragma unroll
    for (int r = 0; r < 8; ++r) acc[r] = 0.0f;
    for (int k4 = 0; k4 < D / 4; ++k4) {
        const int k = 4 * k4;
        const float w0 = Wd2[(k + 0) * D + t], w1 = Wd2[(k + 1) * D + t];
        const float w2 = Wd2[(k + 2) * D + t], w3 = Wd2[(k + 3) * D + t];
        #pragma unroll
        for (int r = 0; r < 8; ++r) {
            const float4 x = *reinterpret_cast<const float4*>(&hb[r][k]);
            acc[r] += x.x * w0 + x.y * w1 + x.z * w2 + x.w * w3;
        }
    }
    for (int r = 0; r < 8; ++r) {
        const int row = r0 + r;
        const int n = row & (NAG - 1);
        const float d = (acc[r] + bd2[t]) * (1.0f + 0.1f * pers[n * D + t]);
        db[r][t]     = d;
        xb[r][t]     = prev[row * D + t];
        xb[r][t + D] = d;
    }
    __syncthreads();

    // 5. GEMM3 gate (K=512); s = g*dec + (1-g)*prev
    #pragma unroll
    for (int r = 0; r < 8; ++r) acc[r] = 0.0f;
    for (int k4 = 0; k4 < D2 / 4; ++k4) {
        const int k = 4 * k4;
        const float w0 = Wg[(k + 0) * D + t], w1 = Wg[(k + 1) * D + t];
        const float w2 = Wg[(k + 2) * D + t], w3 = Wg[(k + 3) * D + t];
        #pragma unroll
        for (int r = 0; r < 8; ++r) {
            const float4 x = *reinterpret_cast<const float4*>(&xb[r][k]);
            acc[r] += x.x * w0 + x.y * w1 + x.z * w2 + x.w * w3;
        }
    }
    for (int r = 0; r < 8; ++r) {
        const float g = sigmoid_f(acc[r] + bg[t]);
        nsb[r][t] = g * db[r][t] + (1.0f - g) * xb[r][t];
    }
    __syncthreads();

    // 6. LN over 256 -> new_states
    for (int r = 0; r < 8; ++r) {
        const float v = nsb[r][t];
        red[t] = v; __syncthreads();
        for (int s = 128; s > 0; s >>= 1) { if (t < s) red[t] += red[t + s]; __syncthreads(); }
        const float mu = red[0] * (1.0f / 256.0f);
        __syncthreads();
        const float c = v - mu;
        red[t] = c * c; __syncthreads();
        for (int s = 128; s > 0; s >>= 1) { if (t < s) red[t] += red[t + s]; __syncthreads(); }
        const float rstd = rsqrtf(red[0] * (1.0f / 256.0f) + 1e-5f);
        __syncthreads();
        const float ns = c * rstd * lnog[t] + lnob[t];
        nsb[r][t] = ns;
        out_st[(r0 + r) * D + t] = ns;
    }
    __syncthreads();

    // 7. GEMM4 actions (K=256)
    #pragma unroll
    for (int r = 0; r < 8; ++r) acc[r] = 0.0f;
    for (int k4 = 0; k4 < D / 4; ++k4) {
        const int k = 4 * k4;
        const float w0 = Wa[(k + 0) * D + t], w1 = Wa[(k + 1) * D + t];
        const float w2 = Wa[(k + 2) * D + t], w3 = Wa[(k + 3) * D + t];
        #pragma unroll
        for (int r = 0; r < 8; ++r) {
            const float4 x = *reinterpret_cast<const float4*>(&nsb[r][k]);
            acc[r] += x.x * w0 + x.y * w1 + x.z * w2 + x.w * w3;
        }
    }
    for (int r = 0; r < 8; ++r)
        out_act[(r0 + r) * D + t] = acc[r] + ba[t];

    // 8. mem_gate = sigmoid(dot(ns, Wm[0:D]) + hdcdot + b_mem)
    const float wmv = Wm[t];
    for (int r = 0; r < 8; ++r) {
        const int row = r0 + r;
        red[t] = nsb[r][t] * wmv; __syncthreads();
        for (int s = 128; s > 0; s >>= 1) { if (t < s) red[t] += red[t + s]; __syncthreads(); }
        if (t == 0) {
            float dotv = 0.0f;
            for (int i = 0; i < 16; ++i) dotv += dot_part[i * NROWS + row];
            out_mg[row] = sigmoid_f(red[0] + dotv + bm[0]);
        }
        __syncthreads();
    }
}

// ---------------------------------------------------------------- K5: exp_hdc GEMM + episodic write
__global__ __launch_bounds__(256) void k_exp_write(
    const float* __restrict__ st, const float* __restrict__ Wh,
    const float* __restrict__ bh, const float* __restrict__ ep,
    const float* __restrict__ key, const float* __restrict__ mg,
    float* __restrict__ out_exp, float* __restrict__ out_nep)
{
    __shared__ __align__(16) float xs[16][D];
    const int t = threadIdx.x;
    const int r0 = blockIdx.y * 16;
    const int hbase = blockIdx.x * 512;

    for (int i = t; i < 16 * D; i += 256)
        xs[i >> 8][i & 255] = st[(r0 + (i >> 8)) * D + (i & 255)];
    __syncthreads();

    const int h0 = hbase + t, h1 = hbase + 256 + t;
    float a0[16], a1[16];
    #pragma unroll
    for (int r = 0; r < 16; ++r) { a0[r] = 0.0f; a1[r] = 0.0f; }

    for (int k4 = 0; k4 < D / 4; ++k4) {
        const int k = 4 * k4;
        const float w00 = Wh[(k + 0) * HH + h0], w01 = Wh[(k + 1) * HH + h0],
                    w02 = Wh[(k + 2) * HH + h0], w03 = Wh[(k + 3) * HH + h0];
        const float w10 = Wh[(k + 0) * HH + h1], w11 = Wh[(k + 1) * HH + h1],
                    w12 = Wh[(k + 2) * HH + h1], w13 = Wh[(k + 3) * HH + h1];
        #pragma unroll
        for (int r = 0; r < 16; ++r) {
            const float4 x = *reinterpret_cast<const float4*>(&xs[r][k]);
            a0[r] += x.x * w00 + x.y * w01 + x.z * w02 + x.w * w03;
            a1[r] += x.x * w10 + x.y * w11 + x.z * w12 + x.w * w13;
        }
    }

    const float b0 = bh[h0], b1 = bh[h1];
    for (int r = 0; r < 16; ++r) {
        const int row = r0 + r, n = row & (NAG - 1);
        const float q0 = tanhf(a0[r] + b0), q1 = tanhf(a1[r] + b1);
        out_exp[row * HH + h0] = q0;
        out_exp[row * HH + h1] = q1;
        const float m = mg[row];
        out_nep[row * HH + h0] = 0.95f * ep[row * HH + h0] + m * q0 * key[n * HH + h0];
        out_nep[row * HH + h1] = 0.95f * ep[row * HH + h1] + m * q1 * key[n * HH + h1];
    }
}

// ----------------------------------------------------------------
extern "C" void kernel_launch(void* const* d_in, const int* in_sizes, int n_in,
                              void* d_out, int out_size, void* d_ws, size_t ws_size,
                              hipStream_t stream)
{
    const float* sig   = (const float*)d_in[0];
    const float* act   = (const float*)d_in[1];
    const float* ep    = (const float*)d_in[2];
    const float* cr    = (const float*)d_in[3];
    const float* prev  = (const float*)d_in[4];
    // d_in[5] = step (unused)
    const float* lnpg  = (const float*)d_in[6];
    const float* lnpb  = (const float*)d_in[7];
    const float* Wp    = (const float*)d_in[8];
    const float* bp    = (const float*)d_in[9];
    const float* lndg  = (const float*)d_in[10];
    const float* lndb  = (const float*)d_in[11];
    const float* Wd1   = (const float*)d_in[12];
    const float* bd1   = (const float*)d_in[13];
    const float* Wd2   = (const float*)d_in[14];
    const float* bd2   = (const float*)d_in[15];
    const float* Wg    = (const float*)d_in[16];
    const float* bg    = (const float*)d_in[17];
    const float* Wa    = (const float*)d_in[18];
    const float* ba    = (const float*)d_in[19];
    const float* Wh    = (const float*)d_in[20];
    const float* bh    = (const float*)d_in[21];
    const float* Wf    = (const float*)d_in[22];
    const float* bfrom = (const float*)d_in[23];
    const float* Wm    = (const float*)d_in[24];
    const float* bm    = (const float*)d_in[25];
    const float* pers  = (const float*)d_in[26];
    const float* chr   = (const float*)d_in[27];
    const float* key   = (const float*)d_in[28];
    const float* lnog  = (const float*)d_in[29];
    const float* lnob  = (const float*)d_in[30];

    float* outp    = (float*)d_out;
    float* out_act = outp;                  // (B,N,D)   524288
    float* out_st  = outp + 524288;         // (B,N,D)   524288
    float* out_nep = outp + 1048576;        // (B,N,H)   16777216
    float* out_exp = outp + 17825792;       // (B,N,H)   16777216
    float* out_mg  = outp + 34603008;       // (B,N,1)   2048

    // scratch: sim_part[16][2048] + dot_part[16][2048] + perc[2048*256] + rpart[4][2048*256]
    const size_t needF = 32768ull + 32768ull + 524288ull + (size_t)KS * 524288ull;
    float* scratch = (ws_size >= needF * sizeof(float)) ? (float*)d_ws
                                                        : out_exp;  // out_exp region free until K5
    float* sim_part = scratch;
    float* dot_part = scratch + 32768;
    float* perc     = scratch + 65536;
    float* rpart    = scratch + 65536 + 524288;

    k_perception<<<dim3(NROWS / 8), dim3(256), 0, stream>>>(
        sig, act, pers, chr, lnpg, lnpb, Wp, bp, perc);

    k_hdc_query<<<dim3(HH / 512, NROWS / 16), dim3(256), 0, stream>>>(
        perc, Wh, bh, ep, cr, key, Wm, sim_part, dot_part);

    k_recall<<<dim3(KS, NROWS / 16), dim3(128), 0, stream>>>(ep, cr, Wf, rpart);

    k_decision<<<dim3(NROWS / 8), dim3(256), 0, stream>>>(
        perc, rpart, bfrom, sim_part, lndg, lndb, Wd1, bd1, Wd2, bd2,
        pers, prev, Wg, bg, lnog, lnob, Wa, ba, Wm, bm, dot_part,
        out_act, out_st, out_mg);

    k_exp_write<<<dim3(HH / 512, NROWS / 16), dim3(256), 0, stream>>>(
        out_st, Wh, bh, ep, key, out_mg, out_exp, out_nep);
}

// Round 2
// 390.919 us; speedup vs baseline: 2.5181x; 2.5181x over previous
//
#include <hip/hip_runtime.h>
#include <hip/hip_bf16.h>
#include <math.h>

#define D     256
#define D2    512
#define HH    8192
#define NAG   64
#define NROWS 2048
#define KSPL  8     // recall K-split
#define HSPL  16    // query/exp h-split

typedef short  s16x8 __attribute__((ext_vector_type(8)));
typedef __bf16 b16x8 __attribute__((ext_vector_type(8)));
typedef float  f32x4 __attribute__((ext_vector_type(4)));

// MFMA wrapper robust to either builtin signature (short8 or __bf16x8): bitcast.
template <typename T>
__device__ __forceinline__ auto mfma_try(T a, T b, f32x4 c, int)
    -> decltype(__builtin_amdgcn_mfma_f32_16x16x32_bf16(a, b, c, 0, 0, 0))
{ return __builtin_amdgcn_mfma_f32_16x16x32_bf16(a, b, c, 0, 0, 0); }

template <typename T>
__device__ __forceinline__ f32x4 mfma_try(T a, T b, f32x4 c, long)
{
    return __builtin_amdgcn_mfma_f32_16x16x32_bf16(
        __builtin_bit_cast(b16x8, a), __builtin_bit_cast(b16x8, b), c, 0, 0, 0);
}

__device__ __forceinline__ f32x4 MFMA(s16x8 a, s16x8 b, f32x4 c)
{ return mfma_try(a, b, c, 0); }

__device__ __forceinline__ float gelu_f(float x) {
    return 0.5f * x * (1.0f + erff(x * 0.70710678118654752440f));
}
__device__ __forceinline__ float sigmoid_f(float x) {
    return 1.0f / (1.0f + expf(-x));
}
__device__ __forceinline__ short f2bf(float x) {
    __hip_bfloat16 h(x);
    return __builtin_bit_cast(short, h);
}
__device__ __forceinline__ float bf2f(short s) {
    unsigned u = ((unsigned)(unsigned short)s) << 16;
    return __builtin_bit_cast(float, u);
}

// ------------------------------------------------ prep: transpose f32 -> bf16
// dst[c][r] = bf16(src[r][c]); R,C multiples of 64.
__global__ __launch_bounds__(256) void k_transpose_bf(
    const float* __restrict__ src, short* __restrict__ dst, int R, int C, int Ctiles)
{
    __shared__ float tl[64][65];
    const int t = threadIdx.x;
    const int bc = blockIdx.x % Ctiles, br = blockIdx.x / Ctiles;
    const int r0 = br * 64, c0 = bc * 64;
    for (int p = 0; p < 16; ++p) {
        int e = p * 256 + t; int i = e >> 6, j = e & 63;
        tl[i][j] = src[(size_t)(r0 + i) * C + c0 + j];
    }
    __syncthreads();
    for (int p = 0; p < 16; ++p) {
        int e = p * 256 + t; int jj = e >> 6, ii = e & 63;
        dst[(size_t)(c0 + jj) * R + r0 + ii] = f2bf(tl[ii][jj]);
    }
}

// ------------------------------------------------ prep: ebf = bf16(ep+cr)
__global__ __launch_bounds__(256) void k_prep_e(
    const float* __restrict__ ep, const float* __restrict__ cr, short* __restrict__ ebf)
{
    const size_t i0 = ((size_t)blockIdx.x * 256 + threadIdx.x) * 8;
    const size_t stride = (size_t)gridDim.x * 256 * 8;
    for (size_t i = i0; i < (size_t)NROWS * HH; i += stride) {
        float4 e0 = *(const float4*)(ep + i), e1 = *(const float4*)(ep + i + 4);
        float4 c0 = *(const float4*)(cr + i), c1 = *(const float4*)(cr + i + 4);
        s16x8 v;
        v[0] = f2bf(e0.x + c0.x); v[1] = f2bf(e0.y + c0.y);
        v[2] = f2bf(e0.z + c0.z); v[3] = f2bf(e0.w + c0.w);
        v[4] = f2bf(e1.x + c1.x); v[5] = f2bf(e1.y + c1.y);
        v[6] = f2bf(e1.z + c1.z); v[7] = f2bf(e1.w + c1.w);
        *(s16x8*)(ebf + i) = v;
    }
}

// ------------------------------------------------ K1: perception (+bf16 copy)
__global__ __launch_bounds__(256) void k_perception(
    const float* __restrict__ sig, const float* __restrict__ act,
    const float* __restrict__ pers, const float* __restrict__ chr,
    const float* __restrict__ lng, const float* __restrict__ lnb,
    const float* __restrict__ Wp, const float* __restrict__ bp,
    float* __restrict__ perc, short* __restrict__ percbf)
{
    __shared__ __align__(16) float xb[8][D2];
    __shared__ float red[256];
    const int t = threadIdx.x;
    const int r0 = blockIdx.x * 8;

    for (int r = 0; r < 8; ++r) {
        const int row = r0 + r;
        const int n = row & (NAG - 1);
        const float p = pers[n * D + t] + 0.3f * chr[n * D + t];
        xb[r][t]     = sig[row * D + t] * (1.0f + 0.1f * p);
        xb[r][t + D] = act[row * D + t];
    }
    __syncthreads();

    for (int r = 0; r < 8; ++r) {
        float a = xb[r][t], b = xb[r][t + D];
        red[t] = a + b; __syncthreads();
        for (int s = 128; s > 0; s >>= 1) { if (t < s) red[t] += red[t + s]; __syncthreads(); }
        const float mu = red[0] * (1.0f / 512.0f);
        __syncthreads();
        a -= mu; b -= mu;
        red[t] = a * a + b * b; __syncthreads();
        for (int s = 128; s > 0; s >>= 1) { if (t < s) red[t] += red[t + s]; __syncthreads(); }
        const float rstd = rsqrtf(red[0] * (1.0f / 512.0f) + 1e-5f);
        __syncthreads();
        xb[r][t]     = a * rstd * lng[t]     + lnb[t];
        xb[r][t + D] = b * rstd * lng[t + D] + lnb[t + D];
    }
    __syncthreads();

    float acc[8];
    #pragma unroll
    for (int r = 0; r < 8; ++r) acc[r] = 0.0f;
    for (int k4 = 0; k4 < D2 / 4; ++k4) {
        const int k = 4 * k4;
        const float w0 = Wp[(k + 0) * D + t];
        const float w1 = Wp[(k + 1) * D + t];
        const float w2 = Wp[(k + 2) * D + t];
        const float w3 = Wp[(k + 3) * D + t];
        #pragma unroll
        for (int r = 0; r < 8; ++r) {
            const float4 x = *reinterpret_cast<const float4*>(&xb[r][k]);
            acc[r] += x.x * w0 + x.y * w1 + x.z * w2 + x.w * w3;
        }
    }
    const float bb = bp[t];
    for (int r = 0; r < 8; ++r) {
        const float v = gelu_f(acc[r] + bb);
        perc[(r0 + r) * D + t]   = v;
        percbf[(r0 + r) * D + t] = f2bf(v);
    }
}

// ------------------------------------------------ K2: MFMA query GEMM + sim/dot partials
// q = tanh(perc @ Wh + bh); sim_part = sum_h e*key*q; dot_part = sum_h q*Wm[D+h]
__global__ __launch_bounds__(256) void k_query(
    const short* __restrict__ percbf, const short* __restrict__ WhT,
    const float* __restrict__ bh, const short* __restrict__ ebf,
    const float* __restrict__ keyf, const float* __restrict__ Wm,
    float* __restrict__ sim_part, float* __restrict__ dot_part)
{
    __shared__ __align__(16) short percs[64 * 256];   // 32 KB, swizzled
    __shared__ __align__(16) short whs[16 * 256];     // 8 KB, swizzled
    __shared__ __align__(16) short es[64 * 20];       // stride 20 (bank spread)
    __shared__ __align__(16) short ks2[64 * 20];
    const int t = threadIdx.x;
    const int l = t & 63, w = t >> 6;
    const int l15 = l & 15, lg = l >> 4;
    const int r0 = blockIdx.y * 64;
    const int hb0 = blockIdx.x * (HH / HSPL);         // 512-wide h chunk
    const int axor = (l15 & 7) << 4;

    for (int p = 0; p < 8; ++p) {
        int e = p * 2048 + t * 8; int r = e >> 8, k = e & 255;
        s16x8 v = *(const s16x8*)(percbf + (r0 + r) * 256 + k);
        *(s16x8*)((char*)percs + r * 512 + ((k * 2) ^ ((r & 7) << 4))) = v;
    }
    __syncthreads();

    // hoist A fragments (constant across n-tiles)
    const int arow = (w * 16 + l15) * 512;
    s16x8 afr[8];
    #pragma unroll
    for (int ks = 0; ks < 8; ++ks)
        afr[ks] = *(const s16x8*)((const char*)percs + arow + ((ks * 64 + lg * 16) ^ axor));

    float psim[4] = {0, 0, 0, 0}, pdot[4] = {0, 0, 0, 0};

    for (int nt = 0; nt < (HH / HSPL) / 16; ++nt) {
        const int hg0 = hb0 + nt * 16;
        // stage whs [16][256]
        for (int p = 0; p < 2; ++p) {
            int e = p * 2048 + t * 8; int hh = e >> 8, k = e & 255;
            s16x8 v = *(const s16x8*)(WhT + (size_t)(hg0 + hh) * 256 + k);
            *(s16x8*)((char*)whs + hh * 512 + ((k * 2) ^ ((hh & 7) << 4))) = v;
        }
        // stage e, key tiles [64][16]
        {
            int e = t * 4; int r = e >> 4, hh = e & 15;
            short4 v = *(const short4*)(ebf + (size_t)(r0 + r) * HH + hg0 + hh);
            es[r * 20 + hh + 0] = v.x; es[r * 20 + hh + 1] = v.y;
            es[r * 20 + hh + 2] = v.z; es[r * 20 + hh + 3] = v.w;
            float4 kv = *(const float4*)(keyf + (size_t)r * HH + hg0 + hh);
            ks2[r * 20 + hh + 0] = f2bf(kv.x); ks2[r * 20 + hh + 1] = f2bf(kv.y);
            ks2[r * 20 + hh + 2] = f2bf(kv.z); ks2[r * 20 + hh + 3] = f2bf(kv.w);
        }
        __syncthreads();

        f32x4 acc = {0.f, 0.f, 0.f, 0.f};
        #pragma unroll
        for (int ks = 0; ks < 8; ++ks) {
            s16x8 b = *(const s16x8*)((const char*)whs + l15 * 512 + ((ks * 64 + lg * 16) ^ axor));
            acc = MFMA(afr[ks], b, acc);
        }
        const int h = hg0 + l15;
        const float bhv = bh[h];
        const float wmv = Wm[D + h];
        #pragma unroll
        for (int j = 0; j < 4; ++j) {
            const int rl = w * 16 + lg * 4 + j;
            const float q = tanhf(acc[j] + bhv);
            psim[j] += q * bf2f(es[rl * 20 + l15]) * bf2f(ks2[rl * 20 + l15]);
            pdot[j] += q * wmv;
        }
        __syncthreads();
    }

    #pragma unroll
    for (int j = 0; j < 4; ++j) {
        float s = psim[j], d = pdot[j];
        for (int m = 1; m < 16; m <<= 1) { s += __shfl_xor(s, m); d += __shfl_xor(d, m); }
        if (l15 == 0) {
            const int row = r0 + w * 16 + lg * 4 + j;
            sim_part[blockIdx.x * NROWS + row] = s;
            dot_part[blockIdx.x * NROWS + row] = d;
        }
    }
}

// ------------------------------------------------ K3: MFMA recall GEMM (K-split x8)
__global__ __launch_bounds__(256) void k_recall(
    const short* __restrict__ ebf, const short* __restrict__ WfT,
    float* __restrict__ rpart)
{
    __shared__ __align__(16) short as_[64 * 64];   // 8 KB
    __shared__ __align__(16) short bs[256 * 64];   // 32 KB
    const int t = threadIdx.x, l = t & 63, w = t >> 6;
    const int l15 = l & 15, lg = l >> 4;
    const int r0 = blockIdx.y * 64;
    const int kc0 = blockIdx.x * (HH / KSPL);
    const int axor = (l15 & 7) << 4;

    f32x4 acc[16];
    #pragma unroll
    for (int i = 0; i < 16; ++i) acc[i] = {0.f, 0.f, 0.f, 0.f};

    for (int kk = 0; kk < HH / KSPL; kk += 64) {
        __syncthreads();
        for (int p = 0; p < 2; ++p) {   // A tile [64][64]
            int e = p * 2048 + t * 8; int r = e >> 6, k = e & 63;
            s16x8 v = *(const s16x8*)(ebf + (size_t)(r0 + r) * HH + kc0 + kk + k);
            *(s16x8*)((char*)as_ + r * 128 + ((k * 2) ^ ((r & 7) << 4))) = v;
        }
        for (int p = 0; p < 8; ++p) {   // B tile [256][64]
            int e = p * 2048 + t * 8; int n = e >> 6, k = e & 63;
            s16x8 v = *(const s16x8*)(WfT + (size_t)n * HH + kc0 + kk + k);
            *(s16x8*)((char*)bs + n * 128 + ((k * 2) ^ ((n & 7) << 4))) = v;
        }
        __syncthreads();
        const int abase = (w * 16 + l15) * 128;
        s16x8 a0 = *(const s16x8*)((const char*)as_ + abase + ((lg * 16) ^ axor));
        s16x8 a1 = *(const s16x8*)((const char*)as_ + abase + ((64 + lg * 16) ^ axor));
        #pragma unroll
        for (int nt = 0; nt < 16; ++nt) {
            const int bbase = (nt * 16 + l15) * 128;
            s16x8 b0 = *(const s16x8*)((const char*)bs + bbase + ((lg * 16) ^ axor));
            s16x8 b1 = *(const s16x8*)((const char*)bs + bbase + ((64 + lg * 16) ^ axor));
            acc[nt] = MFMA(a0, b0, acc[nt]);
            acc[nt] = MFMA(a1, b1, acc[nt]);
        }
    }
    #pragma unroll
    for (int nt = 0; nt < 16; ++nt) {
        #pragma unroll
        for (int j = 0; j < 4; ++j) {
            const int row = r0 + w * 16 + lg * 4 + j;
            rpart[((size_t)blockIdx.x * NROWS + row) * D + nt * 16 + l15] = acc[nt][j];
        }
    }
}

// ------------------------------------------------ K4: decision / gate / LN / actions / mem_gate
__global__ __launch_bounds__(256) void k_decision(
    const float* __restrict__ perc, const float* __restrict__ rpart,
    const float* __restrict__ bfrom, const float* __restrict__ sim_part,
    const float* __restrict__ lng, const float* __restrict__ lnb,
    const float* __restrict__ Wd1, const float* __restrict__ bd1,
    const float* __restrict__ Wd2, const float* __restrict__ bd2,
    const float* __restrict__ pers, const float* __restrict__ prev,
    const float* __restrict__ Wg, const float* __restrict__ bg,
    const float* __restrict__ lnog, const float* __restrict__ lnob,
    const float* __restrict__ Wa, const float* __restrict__ ba,
    const float* __restrict__ Wm, const float* __restrict__ bm,
    const float* __restrict__ dot_part,
    float* __restrict__ out_act, float* __restrict__ out_st, float* __restrict__ out_mg,
    short* __restrict__ stbf)
{
    __shared__ __align__(16) float xb[8][D2];
    __shared__ __align__(16) float hb[8][D];
    __shared__ __align__(16) float db[8][D];
    __shared__ __align__(16) float nsb[8][D];
    __shared__ float red[256];
    const int t = threadIdx.x;
    const int r0 = blockIdx.x * 8;

    for (int r = 0; r < 8; ++r) {
        const int row = r0 + r;
        float sraw = 0.0f;
        for (int i = 0; i < HSPL; ++i) sraw += sim_part[i * NROWS + row];
        const float strength = sigmoid_f(sraw * (1.0f / (float)HH));
        float racc = 0.0f;
        for (int ksp = 0; ksp < KSPL; ++ksp) racc += rpart[((size_t)ksp * NROWS + row) * D + t];
        xb[r][t]     = perc[row * D + t];
        xb[r][t + D] = (racc + bfrom[t]) * strength;
    }
    __syncthreads();

    for (int r = 0; r < 8; ++r) {
        float a = xb[r][t], b = xb[r][t + D];
        red[t] = a + b; __syncthreads();
        for (int s = 128; s > 0; s >>= 1) { if (t < s) red[t] += red[t + s]; __syncthreads(); }
        const float mu = red[0] * (1.0f / 512.0f);
        __syncthreads();
        a -= mu; b -= mu;
        red[t] = a * a + b * b; __syncthreads();
        for (int s = 128; s > 0; s >>= 1) { if (t < s) red[t] += red[t + s]; __syncthreads(); }
        const float rstd = rsqrtf(red[0] * (1.0f / 512.0f) + 1e-5f);
        __syncthreads();
        xb[r][t]     = a * rstd * lng[t]     + lnb[t];
        xb[r][t + D] = b * rstd * lng[t + D] + lnb[t + D];
    }
    __syncthreads();

    float acc[8];

    #pragma unroll
    for (int r = 0; r < 8; ++r) acc[r] = 0.0f;
    for (int k4 = 0; k4 < D2 / 4; ++k4) {
        const int k = 4 * k4;
        const float w0 = Wd1[(k + 0) * D + t], w1 = Wd1[(k + 1) * D + t];
        const float w2 = Wd1[(k + 2) * D + t], w3 = Wd1[(k + 3) * D + t];
        #pragma unroll
        for (int r = 0; r < 8; ++r) {
            const float4 x = *reinterpret_cast<const float4*>(&xb[r][k]);
            acc[r] += x.x * w0 + x.y * w1 + x.z * w2 + x.w * w3;
        }
    }
    for (int r = 0; r < 8; ++r) hb[r][t] = gelu_f(acc[r] + bd1[t]);
    __syncthreads();

    #pragma unroll
    for (int r = 0; r < 8; ++r) acc[r] = 0.0f;
    for (int k4 = 0; k4 < D / 4; ++k4) {
        const int k = 4 * k4;
        const float w0 = Wd2[(k + 0) * D + t], w1 = Wd2[(k + 1) * D + t];
        const float w2 = Wd2[(k + 2) * D + t], w3 = Wd2[(k + 3) * D + t];
        #pragma unroll
        for (int r = 0; r < 8; ++r) {
            const float4 x = *reinterpret_cast<const float4*>(&hb[r][k]);
            acc[r] += x.x * w0 + x.y * w1 + x.z * w2 + x.w * w3;
        }
    }
    for (int r = 0; r < 8; ++r) {
        const int row = r0 + r;
        const int n = row & (NAG - 1);
        const float d = (acc[r] + bd2[t]) * (1.0f + 0.1f * pers[n * D + t]);
        db[r][t]     = d;
        xb[r][t]     = prev[row * D + t];
        xb[r][t + D] = d;
    }
    __syncthreads();

    #pragma unroll
    for (int r = 0; r < 8; ++r) acc[r] = 0.0f;
    for (int k4 = 0; k4 < D2 / 4; ++k4) {
        const int k = 4 * k4;
        const float w0 = Wg[(k + 0) * D + t], w1 = Wg[(k + 1) * D + t];
        const float w2 = Wg[(k + 2) * D + t], w3 = Wg[(k + 3) * D + t];
        #pragma unroll
        for (int r = 0; r < 8; ++r) {
            const float4 x = *reinterpret_cast<const float4*>(&xb[r][k]);
            acc[r] += x.x * w0 + x.y * w1 + x.z * w2 + x.w * w3;
        }
    }
    for (int r = 0; r < 8; ++r) {
        const float g = sigmoid_f(acc[r] + bg[t]);
        nsb[r][t] = g * db[r][t] + (1.0f - g) * xb[r][t];
    }
    __syncthreads();

    for (int r = 0; r < 8; ++r) {
        const float v = nsb[r][t];
        red[t] = v; __syncthreads();
        for (int s = 128; s > 0; s >>= 1) { if (t < s) red[t] += red[t + s]; __syncthreads(); }
        const float mu = red[0] * (1.0f / 256.0f);
        __syncthreads();
        const float c = v - mu;
        red[t] = c * c; __syncthreads();
        for (int s = 128; s > 0; s >>= 1) { if (t < s) red[t] += red[t + s]; __syncthreads(); }
        const float rstd = rsqrtf(red[0] * (1.0f / 256.0f) + 1e-5f);
        __syncthreads();
        const float ns = c * rstd * lnog[t] + lnob[t];
        nsb[r][t] = ns;
        out_st[(r0 + r) * D + t] = ns;
        stbf[(r0 + r) * D + t]   = f2bf(ns);
    }
    __syncthreads();

    #pragma unroll
    for (int r = 0; r < 8; ++r) acc[r] = 0.0f;
    for (int k4 = 0; k4 < D / 4; ++k4) {
        const int k = 4 * k4;
        const float w0 = Wa[(k + 0) * D + t], w1 = Wa[(k + 1) * D + t];
        const float w2 = Wa[(k + 2) * D + t], w3 = Wa[(k + 3) * D + t];
        #pragma unroll
        for (int r = 0; r < 8; ++r) {
            const float4 x = *reinterpret_cast<const float4*>(&nsb[r][k]);
            acc[r] += x.x * w0 + x.y * w1 + x.z * w2 + x.w * w3;
        }
    }
    for (int r = 0; r < 8; ++r)
        out_act[(r0 + r) * D + t] = acc[r] + ba[t];

    const float wmv = Wm[t];
    for (int r = 0; r < 8; ++r) {
        const int row = r0 + r;
        red[t] = nsb[r][t] * wmv; __syncthreads();
        for (int s = 128; s > 0; s >>= 1) { if (t < s) red[t] += red[t + s]; __syncthreads(); }
        if (t == 0) {
            float dotv = 0.0f;
            for (int i = 0; i < HSPL; ++i) dotv += dot_part[i * NROWS + row];
            out_mg[row] = sigmoid_f(red[0] + dotv + bm[0]);
        }
        __syncthreads();
    }
}

// ------------------------------------------------ K5: MFMA exp GEMM + episodic write
__global__ __launch_bounds__(256) void k_exp(
    const short* __restrict__ stbf, const short* __restrict__ WhT,
    const float* __restrict__ bh, const float* __restrict__ ep,
    const float* __restrict__ keyf, const float* __restrict__ mg,
    float* __restrict__ out_exp, float* __restrict__ out_nep)
{
    __shared__ __align__(16) short sts[64 * 256];
    __shared__ __align__(16) short whs[16 * 256];
    const int t = threadIdx.x, l = t & 63, w = t >> 6;
    const int l15 = l & 15, lg = l >> 4;
    const int r0 = blockIdx.y * 64;
    const int hb0 = blockIdx.x * (HH / HSPL);
    const int axor = (l15 & 7) << 4;

    for (int p = 0; p < 8; ++p) {
        int e = p * 2048 + t * 8; int r = e >> 8, k = e & 255;
        s16x8 v = *(const s16x8*)(stbf + (r0 + r) * 256 + k);
        *(s16x8*)((char*)sts + r * 512 + ((k * 2) ^ ((r & 7) << 4))) = v;
    }
    float mgv[4];
    #pragma unroll
    for (int j = 0; j < 4; ++j) mgv[j] = mg[r0 + w * 16 + lg * 4 + j];
    __syncthreads();

    const int arow = (w * 16 + l15) * 512;
    s16x8 afr[8];
    #pragma unroll
    for (int ks = 0; ks < 8; ++ks)
        afr[ks] = *(const s16x8*)((const char*)sts + arow + ((ks * 64 + lg * 16) ^ axor));

    for (int nt = 0; nt < (HH / HSPL) / 16; ++nt) {
        const int hg0 = hb0 + nt * 16;
        for (int p = 0; p < 2; ++p) {
            int e = p * 2048 + t * 8; int hh = e >> 8, k = e & 255;
            s16x8 v = *(const s16x8*)(WhT + (size_t)(hg0 + hh) * 256 + k);
            *(s16x8*)((char*)whs + hh * 512 + ((k * 2) ^ ((hh & 7) << 4))) = v;
        }
        __syncthreads();

        f32x4 acc = {0.f, 0.f, 0.f, 0.f};
        #pragma unroll
        for (int ks = 0; ks < 8; ++ks) {
            s16x8 b = *(const s16x8*)((const char*)whs + l15 * 512 + ((ks * 64 + lg * 16) ^ axor));
            acc = MFMA(afr[ks], b, acc);
        }
        const int h = hg0 + l15;
        const float bhv = bh[h];
        #pragma unroll
        for (int j = 0; j < 4; ++j) {
            const int row = r0 + w * 16 + lg * 4 + j;
            const int n = row & (NAG - 1);
            const float q = tanhf(acc[j] + bhv);
            const size_t idx = (size_t)row * HH + h;
            out_exp[idx] = q;
            out_nep[idx] = 0.95f * ep[idx] + mgv[j] * q * keyf[(size_t)n * HH + h];
        }
        __syncthreads();
    }
}

// ----------------------------------------------------------------
extern "C" void kernel_launch(void* const* d_in, const int* in_sizes, int n_in,
                              void* d_out, int out_size, void* d_ws, size_t ws_size,
                              hipStream_t stream)
{
    const float* sig   = (const float*)d_in[0];
    const float* act   = (const float*)d_in[1];
    const float* ep    = (const float*)d_in[2];
    const float* cr    = (const float*)d_in[3];
    const float* prev  = (const float*)d_in[4];
    const float* lnpg  = (const float*)d_in[6];
    const float* lnpb  = (const float*)d_in[7];
    const float* Wp    = (const float*)d_in[8];
    const float* bp    = (const float*)d_in[9];
    const float* lndg  = (const float*)d_in[10];
    const float* lndb  = (const float*)d_in[11];
    const float* Wd1   = (const float*)d_in[12];
    const float* bd1   = (const float*)d_in[13];
    const float* Wd2   = (const float*)d_in[14];
    const float* bd2   = (const float*)d_in[15];
    const float* Wg    = (const float*)d_in[16];
    const float* bg    = (const float*)d_in[17];
    const float* Wa    = (const float*)d_in[18];
    const float* ba    = (const float*)d_in[19];
    const float* Wh    = (const float*)d_in[20];
    const float* bh    = (const float*)d_in[21];
    const float* Wf    = (const float*)d_in[22];
    const float* bfrom = (const float*)d_in[23];
    const float* Wm    = (const float*)d_in[24];
    const float* bm    = (const float*)d_in[25];
    const float* pers  = (const float*)d_in[26];
    const float* chr   = (const float*)d_in[27];
    const float* key   = (const float*)d_in[28];
    const float* lnog  = (const float*)d_in[29];
    const float* lnob  = (const float*)d_in[30];

    float* outp    = (float*)d_out;
    float* out_act = outp;                  // (B,N,D)   524288
    float* out_st  = outp + 524288;         // (B,N,D)   524288
    float* out_nep = outp + 1048576;        // (B,N,H)   16777216
    float* out_exp = outp + 17825792;       // (B,N,H)   16777216
    float* out_mg  = outp + 34603008;       // (B,N)     2048

    // Pre-k_exp scratch lives in out_nep region (dead until k_exp overwrites it).
    short* ebf      = (short*)out_nep;                       // 16.8M bf16 (32 MB)
    float* rpart    = out_nep + 8388608;                     // 8*2048*256 f32 (16 MB)
    short* WfT      = (short*)(out_nep + 8388608 + 4194304); // 2M bf16 (4 MB)
    float* perc     = out_nep + 8388608 + 4194304 + 1048576; // 0.5M f32 (2 MB)
    float* sim_part = perc + 524288;                         // 16*2048
    float* dot_part = sim_part + 32768;                      // 16*2048  (ends < 16.7M)

    // k_exp inputs must NOT live in out regions -> d_ws (needs ~6.3 MB).
    short* WhT    = (short*)d_ws;            // 8192*256 bf16
    short* percbf = WhT + 2097152;           // 2048*256 bf16
    short* stbf   = percbf + 524288;         // 2048*256 bf16

    k_transpose_bf<<<dim3(512), dim3(256), 0, stream>>>(Wh, WhT, 256, HH, HH / 64);
    k_transpose_bf<<<dim3(512), dim3(256), 0, stream>>>(Wf, WfT, HH, D, D / 64);
    k_prep_e<<<dim3(2048), dim3(256), 0, stream>>>(ep, cr, ebf);

    k_perception<<<dim3(NROWS / 8), dim3(256), 0, stream>>>(
        sig, act, pers, chr, lnpg, lnpb, Wp, bp, perc, percbf);

    k_query<<<dim3(HSPL, NROWS / 64), dim3(256), 0, stream>>>(
        percbf, WhT, bh, ebf, key, Wm, sim_part, dot_part);

    k_recall<<<dim3(KSPL, NROWS / 64), dim3(256), 0, stream>>>(ebf, WfT, rpart);

    k_decision<<<dim3(NROWS / 8), dim3(256), 0, stream>>>(
        perc, rpart, bfrom, sim_part, lndg, lndb, Wd1, bd1, Wd2, bd2,
        pers, prev, Wg, bg, lnog, lnob, Wa, ba, Wm, bm, dot_part,
        out_act, out_st, out_mg, stbf);

    k_exp<<<dim3(HSPL, NROWS / 64), dim3(256), 0, stream>>>(
        stbf, WhT, bh, ep, key, out_mg, out_exp, out_nep);
}

// Round 3
// 255.360 us; speedup vs baseline: 3.8548x; 1.5309x over previous
//
#include <hip/hip_runtime.h>
#include <hip/hip_bf16.h>
#include <math.h>

#define D     256
#define D2    512
#define HH    8192
#define NAG   64
#define NROWS 2048
#define KSPL  8     // recall K-split
#define HSPL  16    // query/exp h-split

typedef short  s16x8 __attribute__((ext_vector_type(8)));
typedef __bf16 b16x8 __attribute__((ext_vector_type(8)));
typedef float  f32x4 __attribute__((ext_vector_type(4)));

template <typename T>
__device__ __forceinline__ auto mfma_try(T a, T b, f32x4 c, int)
    -> decltype(__builtin_amdgcn_mfma_f32_16x16x32_bf16(a, b, c, 0, 0, 0))
{ return __builtin_amdgcn_mfma_f32_16x16x32_bf16(a, b, c, 0, 0, 0); }

template <typename T>
__device__ __forceinline__ f32x4 mfma_try(T a, T b, f32x4 c, long)
{
    return __builtin_amdgcn_mfma_f32_16x16x32_bf16(
        __builtin_bit_cast(b16x8, a), __builtin_bit_cast(b16x8, b), c, 0, 0, 0);
}

__device__ __forceinline__ f32x4 MFMA(s16x8 a, s16x8 b, f32x4 c)
{ return mfma_try(a, b, c, 0); }

__device__ __forceinline__ float gelu_f(float x) {
    return 0.5f * x * (1.0f + erff(x * 0.70710678118654752440f));
}
__device__ __forceinline__ float sigmoid_f(float x) {
    return 1.0f / (1.0f + expf(-x));
}
__device__ __forceinline__ short f2bf(float x) {
    __hip_bfloat16 h(x);
    return __builtin_bit_cast(short, h);
}
__device__ __forceinline__ float bf2f(short s) {
    unsigned u = ((unsigned)(unsigned short)s) << 16;
    return __builtin_bit_cast(float, u);
}

// ------------------------------------------------ transpose f32 -> bf16 (generic body)
__device__ __forceinline__ void transpose_body(
    const float* __restrict__ src, short* __restrict__ dst, int R, int C, int lb)
{
    __shared__ float tl[64][65];
    const int t = threadIdx.x;
    const int Ctiles = C >> 6;
    const int bc = lb % Ctiles, br = lb / Ctiles;
    const int r0 = br * 64, c0 = bc * 64;
    for (int p = 0; p < 16; ++p) {
        int e = p * 256 + t; int i = e >> 6, j = e & 63;
        tl[i][j] = src[(size_t)(r0 + i) * C + c0 + j];
    }
    __syncthreads();
    for (int p = 0; p < 16; ++p) {
        int e = p * 256 + t; int jj = e >> 6, ii = e & 63;
        dst[(size_t)(c0 + jj) * R + r0 + ii] = f2bf(tl[ii][jj]);
    }
}

__global__ __launch_bounds__(256) void k_transpose_bf(
    const float* __restrict__ src, short* __restrict__ dst, int R, int C)
{
    transpose_body(src, dst, R, C, blockIdx.x);
}

// 5 small weights in one launch (128 blocks)
__global__ __launch_bounds__(256) void k_transpose_small(
    const float* __restrict__ Wp,  const float* __restrict__ Wd1,
    const float* __restrict__ Wd2, const float* __restrict__ Wg,
    const float* __restrict__ Wa,
    short* __restrict__ WpT,  short* __restrict__ Wd1T,
    short* __restrict__ Wd2T, short* __restrict__ WgT,
    short* __restrict__ WaT)
{
    const int b = blockIdx.x;
    const float* src; short* dst; int R, C, b0;
    if      (b < 32)  { src = Wp;  dst = WpT;  R = 512; C = 256; b0 = 0;   }
    else if (b < 64)  { src = Wd1; dst = Wd1T; R = 512; C = 256; b0 = 32;  }
    else if (b < 80)  { src = Wd2; dst = Wd2T; R = 256; C = 256; b0 = 64;  }
    else if (b < 112) { src = Wg;  dst = WgT;  R = 512; C = 256; b0 = 80;  }
    else              { src = Wa;  dst = WaT;  R = 256; C = 256; b0 = 112; }
    transpose_body(src, dst, R, C, b - b0);
}

// ------------------------------------------------ prep: ebf = bf16(ep+cr)
__global__ __launch_bounds__(256) void k_prep_e(
    const float* __restrict__ ep, const float* __restrict__ cr, short* __restrict__ ebf)
{
    const size_t i0 = ((size_t)blockIdx.x * 256 + threadIdx.x) * 8;
    const size_t stride = (size_t)gridDim.x * 256 * 8;
    for (size_t i = i0; i < (size_t)NROWS * HH; i += stride) {
        float4 e0 = *(const float4*)(ep + i), e1 = *(const float4*)(ep + i + 4);
        float4 c0 = *(const float4*)(cr + i), c1 = *(const float4*)(cr + i + 4);
        s16x8 v;
        v[0] = f2bf(e0.x + c0.x); v[1] = f2bf(e0.y + c0.y);
        v[2] = f2bf(e0.z + c0.z); v[3] = f2bf(e0.w + c0.w);
        v[4] = f2bf(e1.x + c1.x); v[5] = f2bf(e1.y + c1.y);
        v[6] = f2bf(e1.z + c1.z); v[7] = f2bf(e1.w + c1.w);
        *(s16x8*)(ebf + i) = v;
    }
}

// ------------------------------------------------ LN kernels (wave-per-row, shuffle reduce)
__global__ __launch_bounds__(256) void k_ln_perc(
    const float* __restrict__ sig, const float* __restrict__ act,
    const float* __restrict__ pers, const float* __restrict__ chr,
    const float* __restrict__ lng, const float* __restrict__ lnb,
    short* __restrict__ percln)
{
    const int t = threadIdx.x, l = t & 63, w = t >> 6;
    const int row = blockIdx.x * 4 + w;
    const int n = row & (NAG - 1);
    const int c0 = l * 8;
    float v[8];
    if (l < 32) {
        const float* sp = sig  + (size_t)row * D + c0;
        const float* pp = pers + (size_t)n * D + c0;
        const float* cp = chr  + (size_t)n * D + c0;
        float4 s0 = *(const float4*)sp, s1 = *(const float4*)(sp + 4);
        float4 p0 = *(const float4*)pp, p1 = *(const float4*)(pp + 4);
        float4 q0 = *(const float4*)cp, q1 = *(const float4*)(cp + 4);
        v[0] = s0.x * (1.f + 0.1f * (p0.x + 0.3f * q0.x));
        v[1] = s0.y * (1.f + 0.1f * (p0.y + 0.3f * q0.y));
        v[2] = s0.z * (1.f + 0.1f * (p0.z + 0.3f * q0.z));
        v[3] = s0.w * (1.f + 0.1f * (p0.w + 0.3f * q0.w));
        v[4] = s1.x * (1.f + 0.1f * (p1.x + 0.3f * q1.x));
        v[5] = s1.y * (1.f + 0.1f * (p1.y + 0.3f * q1.y));
        v[6] = s1.z * (1.f + 0.1f * (p1.z + 0.3f * q1.z));
        v[7] = s1.w * (1.f + 0.1f * (p1.w + 0.3f * q1.w));
    } else {
        const float* ap = act + (size_t)row * D + (c0 - D);
        float4 a0 = *(const float4*)ap, a1 = *(const float4*)(ap + 4);
        v[0] = a0.x; v[1] = a0.y; v[2] = a0.z; v[3] = a0.w;
        v[4] = a1.x; v[5] = a1.y; v[6] = a1.z; v[7] = a1.w;
    }
    float s = 0.f;
    #pragma unroll
    for (int i = 0; i < 8; ++i) s += v[i];
    #pragma unroll
    for (int m = 1; m < 64; m <<= 1) s += __shfl_xor(s, m);
    const float mu = s * (1.0f / 512.0f);
    float q = 0.f;
    #pragma unroll
    for (int i = 0; i < 8; ++i) { float c = v[i] - mu; q += c * c; }
    #pragma unroll
    for (int m = 1; m < 64; m <<= 1) q += __shfl_xor(q, m);
    const float rstd = rsqrtf(q * (1.0f / 512.0f) + 1e-5f);
    float4 g0 = *(const float4*)(lng + c0), g1 = *(const float4*)(lng + c0 + 4);
    float4 b0 = *(const float4*)(lnb + c0), b1 = *(const float4*)(lnb + c0 + 4);
    const float gg[8] = {g0.x, g0.y, g0.z, g0.w, g1.x, g1.y, g1.z, g1.w};
    const float bb[8] = {b0.x, b0.y, b0.z, b0.w, b1.x, b1.y, b1.z, b1.w};
    s16x8 o;
    #pragma unroll
    for (int i = 0; i < 8; ++i) o[i] = f2bf((v[i] - mu) * rstd * gg[i] + bb[i]);
    *(s16x8*)(percln + (size_t)row * D2 + c0) = o;
}

__global__ __launch_bounds__(256) void k_ln_dec(
    const short* __restrict__ percbf, const float* __restrict__ rpart,
    const float* __restrict__ bfrom, const float* __restrict__ sim_part,
    const float* __restrict__ lng, const float* __restrict__ lnb,
    short* __restrict__ decln)
{
    const int t = threadIdx.x, l = t & 63, w = t >> 6;
    const int row = blockIdx.x * 4 + w;
    const int c0 = l * 8;
    // strength
    float sr = (l < 16) ? sim_part[l * NROWS + row] : 0.f;
    #pragma unroll
    for (int m = 1; m < 16; m <<= 1) sr += __shfl_xor(sr, m);
    sr = __shfl(sr, 0);
    const float strength = sigmoid_f(sr * (1.0f / (float)HH));

    float v[8];
    if (l < 32) {
        s16x8 pv = *(const s16x8*)(percbf + (size_t)row * D + c0);
        #pragma unroll
        for (int i = 0; i < 8; ++i) v[i] = bf2f(pv[i]);
    } else {
        const int c = c0 - D;
        float a[8] = {0, 0, 0, 0, 0, 0, 0, 0};
        for (int ks = 0; ks < KSPL; ++ks) {
            const float* rp = rpart + ((size_t)ks * NROWS + row) * D + c;
            float4 x0 = *(const float4*)rp, x1 = *(const float4*)(rp + 4);
            a[0] += x0.x; a[1] += x0.y; a[2] += x0.z; a[3] += x0.w;
            a[4] += x1.x; a[5] += x1.y; a[6] += x1.z; a[7] += x1.w;
        }
        float4 f0 = *(const float4*)(bfrom + c), f1 = *(const float4*)(bfrom + c + 4);
        const float fb[8] = {f0.x, f0.y, f0.z, f0.w, f1.x, f1.y, f1.z, f1.w};
        #pragma unroll
        for (int i = 0; i < 8; ++i) v[i] = (a[i] + fb[i]) * strength;
    }
    float s = 0.f;
    #pragma unroll
    for (int i = 0; i < 8; ++i) s += v[i];
    #pragma unroll
    for (int m = 1; m < 64; m <<= 1) s += __shfl_xor(s, m);
    const float mu = s * (1.0f / 512.0f);
    float q = 0.f;
    #pragma unroll
    for (int i = 0; i < 8; ++i) { float c = v[i] - mu; q += c * c; }
    #pragma unroll
    for (int m = 1; m < 64; m <<= 1) q += __shfl_xor(q, m);
    const float rstd = rsqrtf(q * (1.0f / 512.0f) + 1e-5f);
    float4 g0 = *(const float4*)(lng + c0), g1 = *(const float4*)(lng + c0 + 4);
    float4 b0 = *(const float4*)(lnb + c0), b1 = *(const float4*)(lnb + c0 + 4);
    const float gg[8] = {g0.x, g0.y, g0.z, g0.w, g1.x, g1.y, g1.z, g1.w};
    const float bb[8] = {b0.x, b0.y, b0.z, b0.w, b1.x, b1.y, b1.z, b1.w};
    s16x8 o;
    #pragma unroll
    for (int i = 0; i < 8; ++i) o[i] = f2bf((v[i] - mu) * rstd * gg[i] + bb[i]);
    *(s16x8*)(decln + (size_t)row * D2 + c0) = o;
}

// ------------------------------------------------ small MFMA GEMM: 16 rows x 256 cols per block
// A [2048][K] bf16, BT [256][K] bf16. EPI: 0=GELU->bf16, 1=dec-scale->bf16, 2=f32 store.
template<int K, int EPI>
__global__ __launch_bounds__(256) void k_gemm16(
    const short* __restrict__ A, const short* __restrict__ BT,
    const float* __restrict__ bias, const float* __restrict__ pers,
    short* __restrict__ outbf, float* __restrict__ outf)
{
    __shared__ __align__(16) short as_[16 * K];
    const int t = threadIdx.x, l = t & 63, w = t >> 6;
    const int l15 = l & 15, lg = l >> 4;
    const int r0 = blockIdx.x * 16;

    #pragma unroll
    for (int p = 0; p < K / 128; ++p) {
        int e = p * 2048 + t * 8;
        int r = e / K, k = e % K;
        s16x8 v = *(const s16x8*)(A + (size_t)(r0 + r) * K + k);
        *(s16x8*)((char*)as_ + r * (2 * K) + ((k * 2) ^ ((r & 7) << 4))) = v;
    }
    __syncthreads();

    s16x8 afr[K / 32];
    const int axor = (l15 & 7) << 4;
    #pragma unroll
    for (int ks = 0; ks < K / 32; ++ks)
        afr[ks] = *(const s16x8*)((const char*)as_ + l15 * (2 * K)
                                  + (((ks * 32 + lg * 8) * 2) ^ axor));

    #pragma unroll
    for (int nt = 0; nt < 4; ++nt) {
        const int col = w * 64 + nt * 16 + l15;
        f32x4 acc = {0.f, 0.f, 0.f, 0.f};
        const short* bp_ = BT + (size_t)col * K + lg * 8;
        #pragma unroll
        for (int ks = 0; ks < K / 32; ++ks)
            acc = MFMA(afr[ks], *(const s16x8*)(bp_ + ks * 32), acc);
        const float bv = bias[col];
        #pragma unroll
        for (int j = 0; j < 4; ++j) {
            const int row = r0 + lg * 4 + j;
            float v = acc[j] + bv;
            if (EPI == 0) {
                outbf[(size_t)row * D + col] = f2bf(gelu_f(v));
            } else if (EPI == 1) {
                v *= (1.0f + 0.1f * pers[(size_t)(row & (NAG - 1)) * D + col]);
                outbf[(size_t)row * D + col] = f2bf(v);
            } else {
                outf[(size_t)row * D + col] = v;
            }
        }
    }
}

// ------------------------------------------------ gate GEMM + blend + LN(256) + mem_gate
__global__ __launch_bounds__(256) void k_gate(
    const float* __restrict__ prev, const short* __restrict__ decbf,
    const short* __restrict__ WgT, const float* __restrict__ bg,
    const float* __restrict__ lnog, const float* __restrict__ lnob,
    const float* __restrict__ Wm, const float* __restrict__ bm,
    const float* __restrict__ dot_part,
    float* __restrict__ out_st, short* __restrict__ stbf,
    float* __restrict__ out_mg)
{
    __shared__ __align__(16) short as_[16 * 512];
    __shared__ float red1[4][16], red2[4][16];
    const int t = threadIdx.x, l = t & 63, w = t >> 6;
    const int l15 = l & 15, lg = l >> 4;
    const int r0 = blockIdx.x * 16;

    // stage concat(prev, dec) as bf16, swizzled
    #pragma unroll
    for (int p = 0; p < 2; ++p) {
        int e = p * 2048 + t * 8;
        int r = e >> 8, c = e & 255;
        const float* pp = prev + (size_t)(r0 + r) * D + c;
        float4 x0 = *(const float4*)pp, x1 = *(const float4*)(pp + 4);
        s16x8 v;
        v[0] = f2bf(x0.x); v[1] = f2bf(x0.y); v[2] = f2bf(x0.z); v[3] = f2bf(x0.w);
        v[4] = f2bf(x1.x); v[5] = f2bf(x1.y); v[6] = f2bf(x1.z); v[7] = f2bf(x1.w);
        *(s16x8*)((char*)as_ + r * 1024 + ((c * 2) ^ ((r & 7) << 4))) = v;
        s16x8 dv = *(const s16x8*)(decbf + (size_t)(r0 + r) * D + c);
        *(s16x8*)((char*)as_ + r * 1024 + (((256 + c) * 2) ^ ((r & 7) << 4))) = dv;
    }
    __syncthreads();

    s16x8 afr[16];
    const int axor = (l15 & 7) << 4;
    #pragma unroll
    for (int ks = 0; ks < 16; ++ks)
        afr[ks] = *(const s16x8*)((const char*)as_ + l15 * 1024
                                  + (((ks * 32 + lg * 8) * 2) ^ axor));

    float sv[4][4];
    #pragma unroll
    for (int nt = 0; nt < 4; ++nt) {
        const int col = w * 64 + nt * 16 + l15;
        f32x4 acc = {0.f, 0.f, 0.f, 0.f};
        const short* bp_ = WgT + (size_t)col * 512 + lg * 8;
        #pragma unroll
        for (int ks = 0; ks < 16; ++ks)
            acc = MFMA(afr[ks], *(const s16x8*)(bp_ + ks * 32), acc);
        const float bgv = bg[col];
        #pragma unroll
        for (int j = 0; j < 4; ++j) {
            const int rl = lg * 4 + j;
            const float pv = bf2f(*(const short*)((const char*)as_ + rl * 1024
                                    + ((col * 2) ^ ((rl & 7) << 4))));
            const float dv = bf2f(*(const short*)((const char*)as_ + rl * 1024
                                    + (((256 + col) * 2) ^ ((rl & 7) << 4))));
            const float g = sigmoid_f(acc[j] + bgv);
            sv[nt][j] = g * dv + (1.0f - g) * pv;
        }
    }

    // row sums / sumsq across 256 cols
    float rs[4], rq[4];
    #pragma unroll
    for (int j = 0; j < 4; ++j) {
        float a = sv[0][j] + sv[1][j] + sv[2][j] + sv[3][j];
        float q = sv[0][j] * sv[0][j] + sv[1][j] * sv[1][j]
                + sv[2][j] * sv[2][j] + sv[3][j] * sv[3][j];
        #pragma unroll
        for (int m = 1; m < 16; m <<= 1) { a += __shfl_xor(a, m); q += __shfl_xor(q, m); }
        rs[j] = a; rq[j] = q;
    }
    if (l15 == 0) {
        #pragma unroll
        for (int j = 0; j < 4; ++j) { red1[w][lg * 4 + j] = rs[j]; red2[w][lg * 4 + j] = rq[j]; }
    }
    __syncthreads();

    float md[4];
    #pragma unroll
    for (int j = 0; j < 4; ++j) {
        const int lr = lg * 4 + j;
        const float tot  = red1[0][lr] + red1[1][lr] + red1[2][lr] + red1[3][lr];
        const float tot2 = red2[0][lr] + red2[1][lr] + red2[2][lr] + red2[3][lr];
        const float mu = tot * (1.0f / 256.0f);
        const float var = tot2 * (1.0f / 256.0f) - mu * mu;
        const float rstd = rsqrtf(var + 1e-5f);
        float m_ = 0.f;
        #pragma unroll
        for (int nt = 0; nt < 4; ++nt) {
            const int col = w * 64 + nt * 16 + l15;
            const float ns = (sv[nt][j] - mu) * rstd * lnog[col] + lnob[col];
            out_st[(size_t)(r0 + lr) * D + col] = ns;
            stbf[(size_t)(r0 + lr) * D + col] = f2bf(ns);
            m_ += ns * Wm[col];
        }
        #pragma unroll
        for (int m = 1; m < 16; m <<= 1) m_ += __shfl_xor(m_, m);
        md[j] = m_;
    }
    __syncthreads();
    if (l15 == 0) {
        #pragma unroll
        for (int j = 0; j < 4; ++j) red1[w][lg * 4 + j] = md[j];
    }
    __syncthreads();
    if (w == 0 && l15 == 0) {
        #pragma unroll
        for (int j = 0; j < 4; ++j) {
            const int lr = lg * 4 + j;
            const float tot = red1[0][lr] + red1[1][lr] + red1[2][lr] + red1[3][lr];
            float dotv = 0.f;
            for (int i = 0; i < HSPL; ++i) dotv += dot_part[i * NROWS + r0 + lr];
            out_mg[r0 + lr] = sigmoid_f(tot + dotv + bm[0]);
        }
    }
}

// ------------------------------------------------ K2: MFMA query GEMM + sim/dot partials
__global__ __launch_bounds__(256) void k_query(
    const short* __restrict__ percbf, const short* __restrict__ WhT,
    const float* __restrict__ bh, const short* __restrict__ ebf,
    const float* __restrict__ keyf, const float* __restrict__ Wm,
    float* __restrict__ sim_part, float* __restrict__ dot_part)
{
    __shared__ __align__(16) short percs[64 * 256];
    __shared__ __align__(16) short whs[16 * 256];
    __shared__ __align__(16) short es[64 * 20];
    __shared__ __align__(16) short ks2[64 * 20];
    const int t = threadIdx.x;
    const int l = t & 63, w = t >> 6;
    const int l15 = l & 15, lg = l >> 4;
    const int r0 = blockIdx.y * 64;
    const int hb0 = blockIdx.x * (HH / HSPL);
    const int axor = (l15 & 7) << 4;

    for (int p = 0; p < 8; ++p) {
        int e = p * 2048 + t * 8; int r = e >> 8, k = e & 255;
        s16x8 v = *(const s16x8*)(percbf + (r0 + r) * 256 + k);
        *(s16x8*)((char*)percs + r * 512 + ((k * 2) ^ ((r & 7) << 4))) = v;
    }
    __syncthreads();

    const int arow = (w * 16 + l15) * 512;
    s16x8 afr[8];
    #pragma unroll
    for (int ks = 0; ks < 8; ++ks)
        afr[ks] = *(const s16x8*)((const char*)percs + arow + ((ks * 64 + lg * 16) ^ axor));

    float psim[4] = {0, 0, 0, 0}, pdot[4] = {0, 0, 0, 0};

    for (int nt = 0; nt < (HH / HSPL) / 16; ++nt) {
        const int hg0 = hb0 + nt * 16;
        for (int p = 0; p < 2; ++p) {
            int e = p * 2048 + t * 8; int hh = e >> 8, k = e & 255;
            s16x8 v = *(const s16x8*)(WhT + (size_t)(hg0 + hh) * 256 + k);
            *(s16x8*)((char*)whs + hh * 512 + ((k * 2) ^ ((hh & 7) << 4))) = v;
        }
        {
            int e = t * 4; int r = e >> 4, hh = e & 15;
            short4 v = *(const short4*)(ebf + (size_t)(r0 + r) * HH + hg0 + hh);
            es[r * 20 + hh + 0] = v.x; es[r * 20 + hh + 1] = v.y;
            es[r * 20 + hh + 2] = v.z; es[r * 20 + hh + 3] = v.w;
            float4 kv = *(const float4*)(keyf + (size_t)r * HH + hg0 + hh);
            ks2[r * 20 + hh + 0] = f2bf(kv.x); ks2[r * 20 + hh + 1] = f2bf(kv.y);
            ks2[r * 20 + hh + 2] = f2bf(kv.z); ks2[r * 20 + hh + 3] = f2bf(kv.w);
        }
        __syncthreads();

        f32x4 acc = {0.f, 0.f, 0.f, 0.f};
        #pragma unroll
        for (int ks = 0; ks < 8; ++ks) {
            s16x8 b = *(const s16x8*)((const char*)whs + l15 * 512 + ((ks * 64 + lg * 16) ^ axor));
            acc = MFMA(afr[ks], b, acc);
        }
        const int h = hg0 + l15;
        const float bhv = bh[h];
        const float wmv = Wm[D + h];
        #pragma unroll
        for (int j = 0; j < 4; ++j) {
            const int rl = w * 16 + lg * 4 + j;
            const float q = tanhf(acc[j] + bhv);
            psim[j] += q * bf2f(es[rl * 20 + l15]) * bf2f(ks2[rl * 20 + l15]);
            pdot[j] += q * wmv;
        }
        __syncthreads();
    }

    #pragma unroll
    for (int j = 0; j < 4; ++j) {
        float s = psim[j], d = pdot[j];
        for (int m = 1; m < 16; m <<= 1) { s += __shfl_xor(s, m); d += __shfl_xor(d, m); }
        if (l15 == 0) {
            const int row = r0 + w * 16 + lg * 4 + j;
            sim_part[blockIdx.x * NROWS + row] = s;
            dot_part[blockIdx.x * NROWS + row] = d;
        }
    }
}

// ------------------------------------------------ K3: MFMA recall GEMM (K-split x8)
__global__ __launch_bounds__(256) void k_recall(
    const short* __restrict__ ebf, const short* __restrict__ WfT,
    float* __restrict__ rpart)
{
    __shared__ __align__(16) short as_[64 * 64];
    __shared__ __align__(16) short bs[256 * 64];
    const int t = threadIdx.x, l = t & 63, w = t >> 6;
    const int l15 = l & 15, lg = l >> 4;
    const int r0 = blockIdx.y * 64;
    const int kc0 = blockIdx.x * (HH / KSPL);
    const int axor = (l15 & 7) << 4;

    f32x4 acc[16];
    #pragma unroll
    for (int i = 0; i < 16; ++i) acc[i] = {0.f, 0.f, 0.f, 0.f};

    for (int kk = 0; kk < HH / KSPL; kk += 64) {
        __syncthreads();
        for (int p = 0; p < 2; ++p) {
            int e = p * 2048 + t * 8; int r = e >> 6, k = e & 63;
            s16x8 v = *(const s16x8*)(ebf + (size_t)(r0 + r) * HH + kc0 + kk + k);
            *(s16x8*)((char*)as_ + r * 128 + ((k * 2) ^ ((r & 7) << 4))) = v;
        }
        for (int p = 0; p < 8; ++p) {
            int e = p * 2048 + t * 8; int n = e >> 6, k = e & 63;
            s16x8 v = *(const s16x8*)(WfT + (size_t)n * HH + kc0 + kk + k);
            *(s16x8*)((char*)bs + n * 128 + ((k * 2) ^ ((n & 7) << 4))) = v;
        }
        __syncthreads();
        const int abase = (w * 16 + l15) * 128;
        s16x8 a0 = *(const s16x8*)((const char*)as_ + abase + ((lg * 16) ^ axor));
        s16x8 a1 = *(const s16x8*)((const char*)as_ + abase + ((64 + lg * 16) ^ axor));
        #pragma unroll
        for (int nt = 0; nt < 16; ++nt) {
            const int bbase = (nt * 16 + l15) * 128;
            s16x8 b0 = *(const s16x8*)((const char*)bs + bbase + ((lg * 16) ^ axor));
            s16x8 b1 = *(const s16x8*)((const char*)bs + bbase + ((64 + lg * 16) ^ axor));
            acc[nt] = MFMA(a0, b0, acc[nt]);
            acc[nt] = MFMA(a1, b1, acc[nt]);
        }
    }
    #pragma unroll
    for (int nt = 0; nt < 16; ++nt) {
        #pragma unroll
        for (int j = 0; j < 4; ++j) {
            const int row = r0 + w * 16 + lg * 4 + j;
            rpart[((size_t)blockIdx.x * NROWS + row) * D + nt * 16 + l15] = acc[nt][j];
        }
    }
}

// ------------------------------------------------ K5: MFMA exp GEMM + episodic write
__global__ __launch_bounds__(256) void k_exp(
    const short* __restrict__ stbf, const short* __restrict__ WhT,
    const float* __restrict__ bh, const float* __restrict__ ep,
    const float* __restrict__ keyf, const float* __restrict__ mg,
    float* __restrict__ out_exp, float* __restrict__ out_nep)
{
    __shared__ __align__(16) short sts[64 * 256];
    __shared__ __align__(16) short whs[16 * 256];
    const int t = threadIdx.x, l = t & 63, w = t >> 6;
    const int l15 = l & 15, lg = l >> 4;
    const int r0 = blockIdx.y * 64;
    const int hb0 = blockIdx.x * (HH / HSPL);
    const int axor = (l15 & 7) << 4;

    for (int p = 0; p < 8; ++p) {
        int e = p * 2048 + t * 8; int r = e >> 8, k = e & 255;
        s16x8 v = *(const s16x8*)(stbf + (r0 + r) * 256 + k);
        *(s16x8*)((char*)sts + r * 512 + ((k * 2) ^ ((r & 7) << 4))) = v;
    }
    float mgv[4];
    #pragma unroll
    for (int j = 0; j < 4; ++j) mgv[j] = mg[r0 + w * 16 + lg * 4 + j];
    __syncthreads();

    const int arow = (w * 16 + l15) * 512;
    s16x8 afr[8];
    #pragma unroll
    for (int ks = 0; ks < 8; ++ks)
        afr[ks] = *(const s16x8*)((const char*)sts + arow + ((ks * 64 + lg * 16) ^ axor));

    for (int nt = 0; nt < (HH / HSPL) / 16; ++nt) {
        const int hg0 = hb0 + nt * 16;
        for (int p = 0; p < 2; ++p) {
            int e = p * 2048 + t * 8; int hh = e >> 8, k = e & 255;
            s16x8 v = *(const s16x8*)(WhT + (size_t)(hg0 + hh) * 256 + k);
            *(s16x8*)((char*)whs + hh * 512 + ((k * 2) ^ ((hh & 7) << 4))) = v;
        }
        __syncthreads();

        f32x4 acc = {0.f, 0.f, 0.f, 0.f};
        #pragma unroll
        for (int ks = 0; ks < 8; ++ks) {
            s16x8 b = *(const s16x8*)((const char*)whs + l15 * 512 + ((ks * 64 + lg * 16) ^ axor));
            acc = MFMA(afr[ks], b, acc);
        }
        const int h = hg0 + l15;
        const float bhv = bh[h];
        #pragma unroll
        for (int j = 0; j < 4; ++j) {
            const int row = r0 + w * 16 + lg * 4 + j;
            const int n = row & (NAG - 1);
            const float q = tanhf(acc[j] + bhv);
            const size_t idx = (size_t)row * HH + h;
            out_exp[idx] = q;
            out_nep[idx] = 0.95f * ep[idx] + mgv[j] * q * keyf[(size_t)n * HH + h];
        }
        __syncthreads();
    }
}

// ----------------------------------------------------------------
extern "C" void kernel_launch(void* const* d_in, const int* in_sizes, int n_in,
                              void* d_out, int out_size, void* d_ws, size_t ws_size,
                              hipStream_t stream)
{
    const float* sig   = (const float*)d_in[0];
    const float* act   = (const float*)d_in[1];
    const float* ep    = (const float*)d_in[2];
    const float* cr    = (const float*)d_in[3];
    const float* prev  = (const float*)d_in[4];
    const float* lnpg  = (const float*)d_in[6];
    const float* lnpb  = (const float*)d_in[7];
    const float* Wp    = (const float*)d_in[8];
    const float* bp    = (const float*)d_in[9];
    const float* lndg  = (const float*)d_in[10];
    const float* lndb  = (const float*)d_in[11];
    const float* Wd1   = (const float*)d_in[12];
    const float* bd1   = (const float*)d_in[13];
    const float* Wd2   = (const float*)d_in[14];
    const float* bd2   = (const float*)d_in[15];
    const float* Wg    = (const float*)d_in[16];
    const float* bg    = (const float*)d_in[17];
    const float* Wa    = (const float*)d_in[18];
    const float* ba    = (const float*)d_in[19];
    const float* Wh    = (const float*)d_in[20];
    const float* bh    = (const float*)d_in[21];
    const float* Wf    = (const float*)d_in[22];
    const float* bfrom = (const float*)d_in[23];
    const float* Wm    = (const float*)d_in[24];
    const float* bm    = (const float*)d_in[25];
    const float* pers  = (const float*)d_in[26];
    const float* chr   = (const float*)d_in[27];
    const float* key   = (const float*)d_in[28];
    const float* lnog  = (const float*)d_in[29];
    const float* lnob  = (const float*)d_in[30];

    float* outp    = (float*)d_out;
    float* out_act = outp;                  // (B,N,D)
    float* out_st  = outp + 524288;         // (B,N,D)
    float* out_nep = outp + 1048576;        // (B,N,H)
    float* out_exp = outp + 17825792;       // (B,N,H)
    float* out_mg  = outp + 34603008;       // (B,N)

    // scratch in out_nep region (dead until k_exp, the last kernel, overwrites it)
    short* ebf      = (short*)out_nep;                       // 16.8M bf16
    float* rpart    = out_nep + 8388608;                     // 8*2048*256 f32
    short* WfT      = (short*)(out_nep + 8388608 + 4194304); // 2M bf16
    float* sim_part = out_nep + 8388608 + 4194304 + 1048576; // 16*2048
    float* dot_part = sim_part + 32768;                      // 16*2048

    // scratch in out_exp region (also dead until k_exp)
    float* oe = out_exp;
    short* percln = (short*)oe;               // 2048x512 bf16
    short* decln  = (short*)(oe + 524288);    // 2048x512 bf16
    short* hbf    = (short*)(oe + 1048576);   // 2048x256 bf16
    short* decbf  = (short*)(oe + 1310720);   // 2048x256 bf16
    short* WpT    = (short*)(oe + 1572864);   // 256x512 bf16
    short* Wd1T   = (short*)(oe + 1638400);   // 256x512
    short* Wd2T   = (short*)(oe + 1703936);   // 256x256
    short* WgT    = (short*)(oe + 1736704);   // 256x512
    short* WaT    = (short*)(oe + 1802240);   // 256x256

    // k_exp inputs in d_ws (~6.3 MB, as validated in R2)
    short* WhT    = (short*)d_ws;            // 8192x256 bf16
    short* percbf = WhT + 2097152;           // 2048x256 bf16
    short* stbf   = percbf + 524288;         // 2048x256 bf16

    k_transpose_bf<<<dim3(512), dim3(256), 0, stream>>>(Wh, WhT, 256, HH);
    k_transpose_bf<<<dim3(512), dim3(256), 0, stream>>>(Wf, WfT, HH, D);
    k_transpose_small<<<dim3(128), dim3(256), 0, stream>>>(
        Wp, Wd1, Wd2, Wg, Wa, WpT, Wd1T, Wd2T, WgT, WaT);
    k_prep_e<<<dim3(2048), dim3(256), 0, stream>>>(ep, cr, ebf);

    k_ln_perc<<<dim3(NROWS / 4), dim3(256), 0, stream>>>(
        sig, act, pers, chr, lnpg, lnpb, percln);
    k_gemm16<512, 0><<<dim3(NROWS / 16), dim3(256), 0, stream>>>(
        percln, WpT, bp, nullptr, percbf, nullptr);

    k_query<<<dim3(HSPL, NROWS / 64), dim3(256), 0, stream>>>(
        percbf, WhT, bh, ebf, key, Wm, sim_part, dot_part);
    k_recall<<<dim3(KSPL, NROWS / 64), dim3(256), 0, stream>>>(ebf, WfT, rpart);

    k_ln_dec<<<dim3(NROWS / 4), dim3(256), 0, stream>>>(
        percbf, rpart, bfrom, sim_part, lndg, lndb, decln);
    k_gemm16<512, 0><<<dim3(NROWS / 16), dim3(256), 0, stream>>>(
        decln, Wd1T, bd1, nullptr, hbf, nullptr);
    k_gemm16<256, 1><<<dim3(NROWS / 16), dim3(256), 0, stream>>>(
        hbf, Wd2T, bd2, pers, decbf, nullptr);
    k_gate<<<dim3(NROWS / 16), dim3(256), 0, stream>>>(
        prev, decbf, WgT, bg, lnog, lnob, Wm, bm, dot_part,
        out_st, stbf, out_mg);
    k_gemm16<256, 2><<<dim3(NROWS / 16), dim3(256), 0, stream>>>(
        stbf, WaT, ba, nullptr, nullptr, out_act);

    k_exp<<<dim3(HSPL, NROWS / 64), dim3(256), 0, stream>>>(
        stbf, WhT, bh, ep, key, out_mg, out_exp, out_nep);
}